// Round 11
// baseline (183.098 us; speedup 1.0000x reference)
//
#include <hip/hip_runtime.h>
#include <hip/hip_bf16.h>

#define IN_CAPS 1152
#define NPASS 2304                    // 8 bt x 288 icq (4 i's each)

typedef __attribute__((ext_vector_type(8))) short bf16x8;   // MFMA A/B frag
typedef __attribute__((ext_vector_type(4))) float f32x4;    // MFMA C/D frag

__device__ __forceinline__ unsigned short f2bf(float f) {   // RNE
    unsigned u = __float_as_uint(f);
    u = u + 0x7fffu + ((u >> 16) & 1u);
    return (unsigned short)(u >> 16);
}
__device__ __forceinline__ unsigned pk2(float lo, float hi) {
    return ((unsigned)f2bf(hi) << 16) | f2bf(lo);
}
__device__ __forceinline__ unsigned cvtpk(float lo, float hi) {   // HW packed cvt (RNE)
    union { __hip_bfloat162 h; unsigned u; } c;
    c.h = __float22bfloat162_rn(make_float2(lo, hi));
    return c.u;
}

// ---- prep (round-0 verified): blocks [0,1152): W -> WB bf16 (same layout);
// [1152,1728): x -> XT[i][b][d] bf16 (transposed for coalesced pass loads) ----
__global__ __launch_bounds__(256)
void conv_xw(const float* __restrict__ W, const float* __restrict__ x,
             unsigned short* __restrict__ WB, unsigned short* __restrict__ XT)
{
    const int tid = threadIdx.x;
    if (blockIdx.x < 1152) {
        size_t g = (size_t)blockIdx.x * 256 + tid;
        const float4* src = (const float4*)(W + g * 8);
        float4 a = src[0], b = src[1];
        uint4 o = {pk2(a.x, a.y), pk2(a.z, a.w), pk2(b.x, b.y), pk2(b.z, b.w)};
        *(uint4*)(WB + g * 8) = o;
    } else {
        const int bx = blockIdx.x - 1152;
        const int i = bx * 2 + (tid >> 7);
        const int b = tid & 127;
        const float4* src = (const float4*)(x + ((size_t)b * IN_CAPS + i) * 8);
        float4 a = src[0], c = src[1];
        uint4 o = {pk2(a.x, a.y), pk2(a.z, a.w), pk2(c.x, c.y), pk2(c.z, c.w)};
        *(uint4*)(XT + ((size_t)i * 128 + b) * 8) = o;
    }
}

// ---- routing pass: 2304 blocks x 128 thr (2 waves). Block = (bt, icq):
// xcd = id&7 owns icq in [xcd*36, xcd*36+36) for all bt -> per-XCD WB slice
// 590 KB (L2-resident). Wave wv handles nn in [wv*8, wv*8+8) for 4 i's.
// D lane (em=b, q): hat[b][e=4q+r][nn] f32. MODE 0: MFMA-C accumulate chain.
// MODE 1: logit = q-shfl-sum of d.pr; softmax over 16 nn needs Z from both
// waves -> 2x16-float LDS exchange, 1 barrier per i (dbuf, WAR-safe).
// Partial: [blk][nn*64+lane] bf16x4 -> 512 B contiguous per store. ----
template<int MODE>
__global__ __launch_bounds__(128, 3)
void caps_pass(const unsigned short* __restrict__ XT, const unsigned short* __restrict__ WB,
               const float* __restrict__ pr, unsigned long long* __restrict__ partial)
{
    const int tid  = threadIdx.x;
    const int wv   = tid >> 6, lane = tid & 63;
    const int em   = lane & 15, q = lane >> 4;
    const int id   = blockIdx.x;
    const int xcd  = id & 7, j = id >> 3;       // j in [0,288)
    const int bt   = j / 36;
    const int icq  = xcd * 36 + j % 36;
    const int i0   = icq * 4;
    const int nb   = wv * 8;                    // this wave's nn base

    __shared__ float zbuf[2][2][16];

    f32x4 acc[8];
    #pragma unroll
    for (int k = 0; k < 8; ++k) acc[k] = (f32x4){0.f, 0.f, 0.f, 0.f};

    float4 prv[8];
    if (MODE) {
        #pragma unroll
        for (int k = 0; k < 8; ++k)   // pr[b_glb][nn][4q..4q+3], i-invariant
            prv[k] = *(const float4*)(pr + (size_t)(bt * 16 + em) * 256 + (nb + k) * 16 + 4 * q);
    }

    #pragma unroll 1
    for (int ii = 0; ii < 4; ++ii) {
        const int i = i0 + ii;
        // B operand: XT[i][b=em] bf16; k>=8 rows zero (kills A garbage)
        uint4 xu = {0u, 0u, 0u, 0u};
        if (q == 0) xu = *(const uint4*)(XT + ((size_t)i * 128 + bt * 16 + em) * 8);
        union { uint4 u; bf16x8 v; } bx; bx.u = xu;

        if (MODE == 0) {
            #pragma unroll
            for (int k = 0; k < 8; ++k) {
                union { uint4 u; bf16x8 v; } ax;
                ax.u = *(const uint4*)(WB + (((size_t)(nb + k) * IN_CAPS + i) * 16 + em) * 8);
                acc[k] = __builtin_amdgcn_mfma_f32_16x16x32_bf16(ax.v, bx.v, acc[k], 0, 0, 0);
            }
        } else {
            f32x4 d[8];
            float p[8], Zw = 0.f;
            #pragma unroll
            for (int k = 0; k < 8; ++k) {
                union { uint4 u; bf16x8 v; } ax;
                ax.u = *(const uint4*)(WB + (((size_t)(nb + k) * IN_CAPS + i) * 16 + em) * 8);
                f32x4 cz = {0.f, 0.f, 0.f, 0.f};
                d[k] = __builtin_amdgcn_mfma_f32_16x16x32_bf16(ax.v, bx.v, cz, 0, 0, 0);
                float t = d[k][0] * prv[k].x + d[k][1] * prv[k].y
                        + d[k][2] * prv[k].z + d[k][3] * prv[k].w;
                t += __shfl_xor(t, 16, 64);     // q-sum: full 16-e logit
                t += __shfl_xor(t, 32, 64);
                p[k] = __expf(t);               // |lg| small -> max-free (proven)
                Zw += p[k];
            }
            if (q == 0) zbuf[ii & 1][wv][em] = Zw;
            __syncthreads();
            float Z = Zw + zbuf[ii & 1][1 - wv][em];
            float rz = __builtin_amdgcn_rcpf(Z);
            #pragma unroll
            for (int k = 0; k < 8; ++k) {
                float c = p[k] * rz;
                acc[k][0] = fmaf(c, d[k][0], acc[k][0]);
                acc[k][1] = fmaf(c, d[k][1], acc[k][1]);
                acc[k][2] = fmaf(c, d[k][2], acc[k][2]);
                acc[k][3] = fmaf(c, d[k][3], acc[k][3]);
            }
        }
    }

    // partial[blk][(nb+k)*64 + lane] = bf16x4 (contiguous 512 B per store)
    unsigned long long* pp = partial + (size_t)id * 1024 + nb * 64 + lane;
    #pragma unroll
    for (int k = 0; k < 8; ++k) {
        union { uint2 u2; unsigned long long ll; } o;
        o.u2 = (uint2){cvtpk(acc[k][0], acc[k][1]), cvtpk(acc[k][2], acc[k][3])};
        pp[k * 64] = o.ll;
    }
}

// ---- reduce 288 bf16 slices per bt + fused B + squash ----
// 64 blocks x 128 thr; gpos = bt*1024 + inner, inner = nn*64 + q*16 + em.
// sid for (bt, icq): (bt*36 + icq%36)*8 + icq/36. Squash row-sum via
// shfl_xor(16/32) over the q lanes. RM 1: pr0 = squash(S/16 + B).
// RM 2: pr2 = pr0 + squash(S + B).  RM 3: out = squash(S + B).
template<int RM>
__global__ __launch_bounds__(128)
void caps_reduce(const unsigned long long* __restrict__ partial,
                 const float* __restrict__ Bb, const float* __restrict__ pr_in,
                 float* __restrict__ outp)
{
    const int gpos = blockIdx.x * 128 + threadIdx.x;   // [0, 8192)
    const int bt = gpos >> 10, inner = gpos & 1023;
    const int nn = inner >> 6, q = (inner >> 4) & 3, em = inner & 15;

    float s0 = 0.f, s1 = 0.f, s2 = 0.f, s3 = 0.f;
    for (int xcd = 0; xcd < 8; ++xcd) {
        #pragma unroll 6
        for (int m = 0; m < 36; ++m) {
            const int sid = (bt * 36 + m) * 8 + xcd;
            union { unsigned long long ll; uint2 u2; } u;
            u.ll = partial[(size_t)sid * 1024 + inner];
            s0 += __uint_as_float(u.u2.x << 16);
            s1 += __uint_as_float(u.u2.x & 0xFFFF0000u);
            s2 += __uint_as_float(u.u2.y << 16);
            s3 += __uint_as_float(u.u2.y & 0xFFFF0000u);
        }
    }
    const float kf = (RM == 1) ? 0.0625f : 1.0f;       // c = softmax(0) = 1/16
    const float4 bb = *(const float4*)(Bb + nn * 16 + 4 * q);
    float v0 = fmaf(s0, kf, bb.x), v1 = fmaf(s1, kf, bb.y);
    float v2 = fmaf(s2, kf, bb.z), v3 = fmaf(s3, kf, bb.w);
    float ss = v0 * v0 + v1 * v1 + v2 * v2 + v3 * v3;
    ss += __shfl_xor(ss, 16, 64);                      // q lanes: 16-apart
    ss += __shfl_xor(ss, 32, 64);
    float sc = sqrtf(ss) / (1.0f + ss);

    const size_t off = ((size_t)(bt * 16 + em) << 8) + (nn << 4) + 4 * q;
    if (RM == 3) {
        *(float4*)(outp + off) = (float4){v0 * sc, v1 * sc, v2 * sc, v3 * sc};
    } else {
        float4 p0 = {0.f, 0.f, 0.f, 0.f};
        if (RM == 2) p0 = *(const float4*)(pr_in + off);
        *(float4*)(outp + off) = (float4){fmaf(v0, sc, p0.x), fmaf(v1, sc, p0.y),
                                          fmaf(v2, sc, p0.z), fmaf(v3, sc, p0.w)};
    }
}

extern "C" void kernel_launch(void* const* d_in, const int* in_sizes, int n_in,
                              void* d_out, int out_size, void* d_ws, size_t ws_size,
                              hipStream_t stream)
{
    const float* x  = (const float*)d_in[0];   // [128,1152,8]
    const float* W  = (const float*)d_in[1];   // [16,1152,16,8]
    const float* Bb = (const float*)d_in[2];   // [16,16]
    float* out = (float*)d_out;                // [128,16,16] fp32

    unsigned long long* partial = (unsigned long long*)d_ws;        // 18.9 MB
    unsigned short* WB = (unsigned short*)(partial + (size_t)NPASS * 1024);  // 4.72 MB
    unsigned short* XT = WB + (size_t)16 * IN_CAPS * 16 * 8;        // 2.36 MB
    float* prA = (float*)(XT + (size_t)128 * IN_CAPS * 8);          // 128 KB
    float* pr2 = prA + 32768;                                       // 128 KB

    conv_xw<<<1728, 256, 0, stream>>>(W, x, WB, XT);
    caps_pass<0><<<NPASS, 128, 0, stream>>>(XT, WB, nullptr, partial);
    caps_reduce<1><<<64, 128, 0, stream>>>(partial, Bb, nullptr, prA);
    caps_pass<1><<<NPASS, 128, 0, stream>>>(XT, WB, prA, partial);
    caps_reduce<2><<<64, 128, 0, stream>>>(partial, Bb, prA, pr2);
    caps_pass<1><<<NPASS, 128, 0, stream>>>(XT, WB, pr2, partial);
    caps_reduce<3><<<64, 128, 0, stream>>>(partial, Bb, nullptr, out);
}

// Round 12
// 150.959 us; speedup vs baseline: 1.2129x; 1.2129x over previous
//
#include <hip/hip_runtime.h>
#include <hip/hip_bf16.h>

#define IN_CAPS 1152
#define NPB 576                        // 144 ic x 4 bq

typedef __attribute__((ext_vector_type(8))) short bf16x8;   // MFMA A/B frag
typedef __attribute__((ext_vector_type(4))) float f32x4;    // MFMA C/D frag

__device__ __forceinline__ unsigned short f2bf(float f) {   // RNE
    unsigned u = __float_as_uint(f);
    u = u + 0x7fffu + ((u >> 16) & 1u);
    return (unsigned short)(u >> 16);
}
__device__ __forceinline__ unsigned pk2(float lo, float hi) {
    return ((unsigned)f2bf(hi) << 16) | f2bf(lo);
}
__device__ __forceinline__ unsigned cvtpk(float lo, float hi) {   // HW packed cvt (RNE)
    union { __hip_bfloat162 h; unsigned u; } c;
    c.h = __float22bfloat162_rn(make_float2(lo, hi));
    return c.u;
}

// ---- prep (verified): blocks [0,1152): W -> WB bf16 (same layout);
// [1152,1728): x -> XT[i][b][d] bf16 (transposed) ----
__global__ __launch_bounds__(256)
void conv_xw(const float* __restrict__ W, const float* __restrict__ x,
             unsigned short* __restrict__ WB, unsigned short* __restrict__ XT)
{
    const int tid = threadIdx.x;
    if (blockIdx.x < 1152) {
        size_t g = (size_t)blockIdx.x * 256 + tid;
        const float4* src = (const float4*)(W + g * 8);
        float4 a = src[0], b = src[1];
        uint4 o = {pk2(a.x, a.y), pk2(a.z, a.w), pk2(b.x, b.y), pk2(b.z, b.w)};
        *(uint4*)(WB + g * 8) = o;
    } else {
        const int bx = blockIdx.x - 1152;
        const int i = bx * 2 + (tid >> 7);
        const int b = tid & 127;
        const float4* src = (const float4*)(x + ((size_t)b * IN_CAPS + i) * 8);
        float4 a = src[0], c = src[1];
        uint4 o = {pk2(a.x, a.y), pk2(a.z, a.w), pk2(c.x, c.y), pk2(c.z, c.w)};
        *(uint4*)(XT + ((size_t)i * 128 + b) * 8) = o;
    }
}

// ---- routing pass: 576 blocks = (ic:144 x bq:4), 256 thr = 4 waves.
// Wave wv: btile t = wv>>1 (b = bq*32 + t*16 + em), nn-half h = wv&1.
// Stage: wlds[i8][nn16][em16] uint4 (32 KB, each byte loaded ONCE) +
// xlds[i8][b32] (4 KB). MFMA A/B frags read from LDS: 4-way q-duplication
// is a same-address broadcast (free) -> global W traffic 147 MB -> 18 MB.
// MODE 0: MFMA-C accumulate chain. MODE 1: logit via q-shfl sum, softmax
// over 16 nn with cross-wave Z exchange (dbuf zbuf, 1 barrier/i; R11-verified).
// Partial: [blk][nn*128 + t*64 + lane] bf16x4 -> 512 B contiguous stores. ----
template<int MODE>
__global__ __launch_bounds__(256)
void caps_pass(const uint4* __restrict__ WB4, const uint4* __restrict__ XT4,
               const float* __restrict__ pr, unsigned long long* __restrict__ partial)
{
    const int tid  = threadIdx.x;
    const int wv   = tid >> 6, lane = tid & 63;
    const int em   = lane & 15, q = lane >> 4;
    const int t    = wv >> 1, h = wv & 1;
    const int blk  = blockIdx.x;
    const int ic   = blk >> 2, bq = blk & 3;
    const int i0   = ic * 8;
    const int b_glb = bq * 32 + t * 16 + em;

    __shared__ __align__(16) uint4 wlds[8 * 16 * 16];   // [i][nn][em] 32 KB
    __shared__ __align__(16) uint4 xlds[8 * 32];        // [i][bloc]   4 KB
    __shared__ float zbuf[2][2][2][16];                 // [par][t][h][em]

    // ---- stage W slice (2048 uint4, each loaded exactly once, coalesced) ----
    #pragma unroll
    for (int j2 = 0; j2 < 8; ++j2) {
        const int u = j2 * 256 + tid;
        const int nn = u >> 7, si = (u >> 4) & 7, sem = u & 15;
        wlds[si * 256 + nn * 16 + sem] =
            WB4[((size_t)nn * IN_CAPS + i0 + si) * 16 + sem];
    }
    // ---- stage x slice ----
    {
        const int si = tid >> 5, bloc = tid & 31;
        xlds[si * 32 + bloc] = XT4[(size_t)(i0 + si) * 128 + bq * 32 + bloc];
    }

    float4 prv[8];
    if (MODE) {
        #pragma unroll
        for (int k = 0; k < 8; ++k)   // pr[b_glb][nn=h*8+k][4q..4q+3]
            prv[k] = *(const float4*)(pr + (size_t)b_glb * 256 + (h * 8 + k) * 16 + 4 * q);
    }

    f32x4 acc[8];
    #pragma unroll
    for (int k = 0; k < 8; ++k) acc[k] = (f32x4){0.f, 0.f, 0.f, 0.f};

    __syncthreads();

    #pragma unroll 1
    for (int ii = 0; ii < 8; ++ii) {
        // B operand: xlds[ii][t*16+em]; k>=8 rows zero (kills A garbage)
        uint4 xu = {0u, 0u, 0u, 0u};
        if (q == 0) xu = xlds[ii * 32 + t * 16 + em];
        union { uint4 u; bf16x8 v; } bx; bx.u = xu;

        if (MODE == 0) {
            #pragma unroll
            for (int k = 0; k < 8; ++k) {
                union { uint4 u; bf16x8 v; } ax;
                ax.u = wlds[ii * 256 + (h * 8 + k) * 16 + em];   // broadcast over q
                acc[k] = __builtin_amdgcn_mfma_f32_16x16x32_bf16(ax.v, bx.v, acc[k], 0, 0, 0);
            }
        } else {
            f32x4 d[8];
            float p[8], Zw = 0.f;
            #pragma unroll
            for (int k = 0; k < 8; ++k) {
                union { uint4 u; bf16x8 v; } ax;
                ax.u = wlds[ii * 256 + (h * 8 + k) * 16 + em];
                f32x4 cz = {0.f, 0.f, 0.f, 0.f};
                d[k] = __builtin_amdgcn_mfma_f32_16x16x32_bf16(ax.v, bx.v, cz, 0, 0, 0);
                float lg = d[k][0] * prv[k].x + d[k][1] * prv[k].y
                         + d[k][2] * prv[k].z + d[k][3] * prv[k].w;
                lg += __shfl_xor(lg, 16, 64);   // q-sum: full 16-e logit
                lg += __shfl_xor(lg, 32, 64);
                p[k] = __expf(lg);              // |lg| small -> max-free (proven)
                Zw += p[k];
            }
            if (q == 0) zbuf[ii & 1][t][h][em] = Zw;
            __syncthreads();
            float Z = Zw + zbuf[ii & 1][t][1 - h][em];
            float rz = __builtin_amdgcn_rcpf(Z);
            #pragma unroll
            for (int k = 0; k < 8; ++k) {
                float c = p[k] * rz;
                acc[k][0] = fmaf(c, d[k][0], acc[k][0]);
                acc[k][1] = fmaf(c, d[k][1], acc[k][1]);
                acc[k][2] = fmaf(c, d[k][2], acc[k][2]);
                acc[k][3] = fmaf(c, d[k][3], acc[k][3]);
            }
        }
    }

    // partial[blk][(h*8+k)*128 + t*64 + lane] bf16x4 (512 B contiguous/store)
    unsigned long long* pp = partial + (size_t)blk * 2048 + (h * 8) * 128 + t * 64 + lane;
    #pragma unroll
    for (int k = 0; k < 8; ++k) {
        union { uint2 u2; unsigned long long ll; } o;
        o.u2 = (uint2){cvtpk(acc[k][0], acc[k][1]), cvtpk(acc[k][2], acc[k][3])};
        pp[k * 128] = o.ll;
    }
}

// ---- reduce 144 ic slices + fused B + squash. 64 blocks x 128 thr.
// blk -> (bq = blk>>4, t = (blk>>3)&1, npair = blk&7); wave wv: n = npair*2+wv.
// Thread (q,em): sums its e-quad over 144 slices; squash row-sum via
// shfl_xor(16/32) over q lanes. RM 1: pr0 = squash(S/16 + B).
// RM 2: pr2 = pr0 + squash(S + B).  RM 3: out = squash(S + B). ----
template<int RM>
__global__ __launch_bounds__(128)
void caps_reduce(const unsigned long long* __restrict__ partial,
                 const float* __restrict__ Bb, const float* __restrict__ pr_in,
                 float* __restrict__ outp)
{
    const int tid = threadIdx.x;
    const int wv = tid >> 6, lane = tid & 63;
    const int q = lane >> 4, em = lane & 15;
    const int blk = blockIdx.x;
    const int bq = blk >> 4, t = (blk >> 3) & 1, npair = blk & 7;
    const int n = npair * 2 + wv;

    float s0 = 0.f, s1 = 0.f, s2 = 0.f, s3 = 0.f;
    #pragma unroll 6
    for (int ic = 0; ic < 144; ++ic) {
        union { unsigned long long ll; uint2 u2; } u;
        u.ll = partial[((size_t)(ic * 4 + bq)) * 2048 + n * 128 + t * 64 + lane];
        s0 += __uint_as_float(u.u2.x << 16);
        s1 += __uint_as_float(u.u2.x & 0xFFFF0000u);
        s2 += __uint_as_float(u.u2.y << 16);
        s3 += __uint_as_float(u.u2.y & 0xFFFF0000u);
    }
    const float kf = (RM == 1) ? 0.0625f : 1.0f;       // c = softmax(0) = 1/16
    const float4 bb = *(const float4*)(Bb + n * 16 + 4 * q);
    float v0 = fmaf(s0, kf, bb.x), v1 = fmaf(s1, kf, bb.y);
    float v2 = fmaf(s2, kf, bb.z), v3 = fmaf(s3, kf, bb.w);
    float ss = v0 * v0 + v1 * v1 + v2 * v2 + v3 * v3;
    ss += __shfl_xor(ss, 16, 64);                      // q lanes: 16-apart
    ss += __shfl_xor(ss, 32, 64);
    float sc = sqrtf(ss) / (1.0f + ss);

    const int b_glb = bq * 32 + t * 16 + em;
    const size_t off = ((size_t)b_glb << 8) + (n << 4) + 4 * q;
    if (RM == 3) {
        *(float4*)(outp + off) = (float4){v0 * sc, v1 * sc, v2 * sc, v3 * sc};
    } else {
        float4 p0 = {0.f, 0.f, 0.f, 0.f};
        if (RM == 2) p0 = *(const float4*)(pr_in + off);
        *(float4*)(outp + off) = (float4){fmaf(v0, sc, p0.x), fmaf(v1, sc, p0.y),
                                          fmaf(v2, sc, p0.z), fmaf(v3, sc, p0.w)};
    }
}

extern "C" void kernel_launch(void* const* d_in, const int* in_sizes, int n_in,
                              void* d_out, int out_size, void* d_ws, size_t ws_size,
                              hipStream_t stream)
{
    const float* x  = (const float*)d_in[0];   // [128,1152,8]
    const float* W  = (const float*)d_in[1];   // [16,1152,16,8]
    const float* Bb = (const float*)d_in[2];   // [16,16]
    float* out = (float*)d_out;                // [128,16,16] fp32

    unsigned long long* partial = (unsigned long long*)d_ws;        // 9.4 MB
    unsigned short* WB = (unsigned short*)(partial + (size_t)NPB * 2048);  // 4.72 MB
    unsigned short* XT = WB + (size_t)16 * IN_CAPS * 16 * 8;        // 2.36 MB
    float* prA = (float*)(XT + (size_t)128 * IN_CAPS * 8);          // 128 KB
    float* pr2 = prA + 32768;                                       // 128 KB

    conv_xw<<<1728, 256, 0, stream>>>(W, x, WB, XT);
    caps_pass<0><<<NPB, 256, 0, stream>>>((const uint4*)WB, (const uint4*)XT, nullptr, partial);
    caps_reduce<1><<<64, 128, 0, stream>>>(partial, Bb, nullptr, prA);
    caps_pass<1><<<NPB, 256, 0, stream>>>((const uint4*)WB, (const uint4*)XT, prA, partial);
    caps_reduce<2><<<64, 128, 0, stream>>>(partial, Bb, prA, pr2);
    caps_pass<1><<<NPB, 256, 0, stream>>>((const uint4*)WB, (const uint4*)XT, pr2, partial);
    caps_reduce<3><<<64, 128, 0, stream>>>(partial, Bb, nullptr, out);
}